// Round 9
// baseline (282.674 us; speedup 1.0000x reference)
//
#include <hip/hip_runtime.h>
#include <math.h>

#define Bn 2
#define Sn 2048
#define Vn 32000
#define Dn 256
#define BSn (Bn * Sn)

typedef unsigned short u16;
typedef __attribute__((ext_vector_type(8))) __bf16 bf16x8;
typedef __attribute__((ext_vector_type(4))) float f32x4;
typedef __attribute__((ext_vector_type(8))) unsigned short u16x8;
typedef __attribute__((ext_vector_type(4))) unsigned short u16x4;

__device__ __forceinline__ u16 f2b(float v) {
    union { __bf16 b; u16 u; } c;
    c.b = (__bf16)v;
    return c.u;
}

// async global->LDS, 16B per lane; LDS dest must be linear in lane order
#define GLOAD16(gp, lp)                                          \
    __builtin_amdgcn_global_load_lds(                            \
        (const __attribute__((address_space(1))) void*)(gp),     \
        (__attribute__((address_space(3))) void*)(lp), 16, 0, 0)

__device__ __forceinline__ float wred_max(float v) {
#pragma unroll
    for (int o = 32; o; o >>= 1) v = fmaxf(v, __shfl_xor(v, o, 64));
    return v;
}
__device__ __forceinline__ float wred_sum(float v) {
#pragma unroll
    for (int o = 32; o; o >>= 1) v += __shfl_xor(v, o, 64);
    return v;
}

// ---------------------------------------------------------------------------
// Prep: 5 D*D weight converts + embed (U is NOT converted — logits reads f32)
// blocks [0,320): weights; [320,4416): embed
// ---------------------------------------------------------------------------
__global__ __launch_bounds__(256) void k_prep(
    const int* __restrict__ inp, const float* __restrict__ E,
    const float* __restrict__ P, const float* __restrict__ WQK1,
    const float* __restrict__ WOV1, const float* __restrict__ WQK2,
    const float* __restrict__ WOV2, const float* __restrict__ WF,
    float* __restrict__ Xf, u16* __restrict__ Xb, u16* __restrict__ Wqv1,
    u16* __restrict__ Wqv2, u16* __restrict__ Wfb) {
    int bid = blockIdx.x;
    if (bid < 320) {
        int w = bid >> 6, blk = bid & 63;
        const float* src;
        u16* dst;
        switch (w) {
            case 0: src = WQK1; dst = Wqv1; break;
            case 1: src = WOV1; dst = Wqv1 + Dn * Dn; break;
            case 2: src = WQK2; dst = Wqv2; break;
            case 3: src = WOV2; dst = Wqv2 + Dn * Dn; break;
            default: src = WF; dst = Wfb; break;
        }
        int i = (blk * 256 + threadIdx.x) * 4;
        float4 v = *(const float4*)&src[i];
        u16x4 o;
        o.x = f2b(v.x); o.y = f2b(v.y); o.z = f2b(v.z); o.w = f2b(v.w);
        *(u16x4*)&dst[i] = o;
    } else {
        int bs = bid - 320;
        int d = threadIdx.x;
        int tok = inp[bs];
        int s = bs & (Sn - 1);
        float v = E[(size_t)tok * Dn + d] + P[(size_t)s * Dn + d];
        Xf[(size_t)bs * Dn + d] = v;
        Xb[(size_t)bs * Dn + d] = f2b(v);
    }
}

// ---------------------------------------------------------------------------
// MFMA GEMM: C[M,N] = alpha * A[M,K] @ B[N,K]^T (+R). bf16 in, f32 acc.
// 128xTN tile (TN=128 or 64), BK=32, 256 thr, dual-buffer LDS, 2-phase
// pipeline. QV_SPLIT: x-tiles bn0>=256 scatter-write transposed V.
// ---------------------------------------------------------------------------
template <bool HAS_RES, bool OUT_F32, bool OUT_BF16, bool CAUSAL_SKIP,
          bool QV_SPLIT, int TN>
__global__ __launch_bounds__(256)
void k_mfma(const u16* __restrict__ A, const u16* __restrict__ Bb,
            const float* __restrict__ R, float* __restrict__ Cf,
            u16* __restrict__ Cb, u16* __restrict__ Ct, int M, int N, int K,
            int lda, int ldb, int ldc, float alpha, long long sA, long long sB,
            long long sC, long long sR) {
    int bx = blockIdx.x, by = blockIdx.y;
    int bm0 = by * 128;
    int bn0 = bx * TN;
    if (CAUSAL_SKIP && bn0 > bm0 + 127) return;

    int zb = blockIdx.z;
    A += (long long)zb * sA;
    Bb += (long long)zb * sB;
    if (HAS_RES) R += (long long)zb * sR;
    if (OUT_F32) Cf += (long long)zb * sC;
    if (OUT_BF16) Cb += (long long)zb * sC;

    __shared__ alignas(16) u16 As[2][128 * 32];
    __shared__ alignas(16) u16 Bs[2][TN * 32];

    int tid = threadIdx.x;
    int lane = tid & 63;
    int wave = tid >> 6;

    constexpr int MF = (TN == 128) ? 4 : 2;
    int wr, wc;
    if (TN == 128) {
        wr = wave >> 1;
        wc = wave & 1;
    } else {
        wr = wave;
        wc = 0;
    }

    int fr = lane & 15;
    int kq = lane >> 4;
    int rq = kq * 4;

    f32x4 acc[MF][4] = {};

    int nt = K >> 5;

    auto STAGE = [&](int buf, int k0) {
#pragma unroll
        for (int c = 0; c < 2; ++c) {
            int idx = tid + c * 256;
            int r = idx >> 2, co = (idx & 3) << 3;
            GLOAD16(&A[(size_t)(bm0 + r) * lda + k0 + co], &As[buf][idx * 8]);
        }
#pragma unroll
        for (int c = 0; c < TN / 64; ++c) {
            int idx = tid + c * 256;
            int r = idx >> 2, co = (idx & 3) << 3;
            GLOAD16(&Bb[(size_t)(bn0 + r) * ldb + k0 + co], &Bs[buf][idx * 8]);
        }
    };

    STAGE(0, 0);
    __syncthreads();

    for (int t = 0; t < nt; ++t) {
        int cur = t & 1;
        if (t + 1 < nt) STAGE(cur ^ 1, (t + 1) << 5);

        bf16x8 a[MF], b[4];
#pragma unroll
        for (int m = 0; m < MF; ++m)
            a[m] = *(const bf16x8*)&As[cur]
                       [(wr * (MF * 16) + m * 16 + fr) * 32 + kq * 8];
#pragma unroll
        for (int n = 0; n < 4; ++n)
            b[n] = *(const bf16x8*)&Bs[cur]
                       [(wc * 64 + n * 16 + fr) * 32 + kq * 8];
#pragma unroll
        for (int m = 0; m < MF; ++m)
#pragma unroll
            for (int n = 0; n < 4; ++n)
                acc[m][n] = __builtin_amdgcn_mfma_f32_16x16x32_bf16(
                    a[m], b[n], acc[m][n], 0, 0, 0);
        __syncthreads();
    }

    // ---- epilogue; C/D layout: col = lane&15, row = (lane>>4)*4 + i ----
    if (QV_SPLIT && bn0 >= 256) {
#pragma unroll
        for (int m = 0; m < MF; ++m) {
#pragma unroll
            for (int n = 0; n < 4; ++n) {
                int gr = bm0 + wr * (MF * 16) + m * 16 + rq;  // s-global
                int gc = bn0 + wc * 64 + n * 16 + fr - 256;   // d
                int bb = gr / Sn;
                int ss = gr % Sn;
                u16x4 o;
#pragma unroll
                for (int i = 0; i < 4; ++i) o[i] = f2b(acc[m][n][i]);
                *(u16x4*)&Ct[((size_t)bb * Dn + gc) * Sn + ss] = o;
            }
        }
        return;
    }

#pragma unroll
    for (int m = 0; m < MF; ++m) {
#pragma unroll
        for (int n = 0; n < 4; ++n) {
            int gr = bm0 + wr * (MF * 16) + m * 16 + rq;
            int gc = bn0 + wc * 64 + n * 16 + fr;
#pragma unroll
            for (int i = 0; i < 4; ++i) {
                float v = acc[m][n][i] * alpha;
                size_t idx = (size_t)(gr + i) * ldc + gc;
                if (HAS_RES) v += R[idx];
                if (OUT_F32) Cf[idx] = v;
                if (OUT_BF16) Cb[idx] = f2b(v);
            }
        }
    }
}

// ---------------------------------------------------------------------------
// Logits GEMM: out[M,Vn] = Fb[M,256] @ U[Vn,256]^T. A bf16 via gload_lds;
// B read as f32 and converted during reg-staging (T14: loads for t+1 issued
// before MFMAs of t, convert+ds_write after). 128x128 tile, 2-phase dbuf,
// XCD-bijective + chunked x-remap for L2 locality.
// ---------------------------------------------------------------------------
template <int CHUNK>
__global__ __launch_bounds__(256)
void k_logits(const u16* __restrict__ A, const float* __restrict__ Uf,
              float* __restrict__ Cf, int ytiles) {
    constexpr int K = 256;
    int nwg = gridDim.x;
    int q = nwg >> 3;
    int bid = blockIdx.x;
    int wg = (bid & 7) * q + (bid >> 3);  // bijective (nwg % 8 == 0)
    int per = CHUNK * ytiles;
    int ch = wg / per, rr = wg % per;
    int bx = ch * CHUNK + rr % CHUNK;
    int by = rr / CHUNK;
    int bm0 = by * 128;
    int bn0 = bx * 128;

    __shared__ alignas(16) u16 As[2][128 * 32];
    __shared__ alignas(16) u16 Bs[2][128 * 32];

    int tid = threadIdx.x;
    int lane = tid & 63;
    int wave = tid >> 6;
    int wr = wave >> 1, wc = wave & 1;
    int fr = lane & 15, kq = lane >> 4, rq = kq * 4;

    f32x4 acc[4][4] = {};

    auto STAGE_A = [&](int buf, int k0) {
#pragma unroll
        for (int c = 0; c < 2; ++c) {
            int idx = tid + c * 256;
            int r = idx >> 2, co = (idx & 3) << 3;
            GLOAD16(&A[(size_t)(bm0 + r) * K + k0 + co], &As[buf][idx * 8]);
        }
    };

    float vv[2][8];
    auto LOAD_B = [&](int k0) {
#pragma unroll
        for (int c = 0; c < 2; ++c) {
            int idx = tid + c * 256;
            int r = idx >> 2, co = (idx & 3) << 3;
            const float* src = &Uf[(size_t)(bn0 + r) * K + k0 + co];
            float4 v0 = *(const float4*)src;
            float4 v1 = *(const float4*)(src + 4);
            vv[c][0] = v0.x; vv[c][1] = v0.y; vv[c][2] = v0.z; vv[c][3] = v0.w;
            vv[c][4] = v1.x; vv[c][5] = v1.y; vv[c][6] = v1.z; vv[c][7] = v1.w;
        }
    };
    auto WRITE_B = [&](int buf) {
#pragma unroll
        for (int c = 0; c < 2; ++c) {
            int idx = tid + c * 256;
            u16x8 o;
#pragma unroll
            for (int e = 0; e < 8; ++e) o[e] = f2b(vv[c][e]);
            *(u16x8*)&Bs[buf][idx * 8] = o;
        }
    };

    LOAD_B(0);
    WRITE_B(0);
    STAGE_A(0, 0);
    __syncthreads();

    for (int t = 0; t < 8; ++t) {
        int cur = t & 1;
        bool pre = (t + 1 < 8);
        if (pre) {
            LOAD_B((t + 1) << 5);        // issue f32 loads early
            STAGE_A(cur ^ 1, (t + 1) << 5);
        }

        bf16x8 a[4], b[4];
#pragma unroll
        for (int m = 0; m < 4; ++m)
            a[m] = *(const bf16x8*)&As[cur][(wr * 64 + m * 16 + fr) * 32 + kq * 8];
#pragma unroll
        for (int n = 0; n < 4; ++n)
            b[n] = *(const bf16x8*)&Bs[cur][(wc * 64 + n * 16 + fr) * 32 + kq * 8];
#pragma unroll
        for (int m = 0; m < 4; ++m)
#pragma unroll
            for (int n = 0; n < 4; ++n)
                acc[m][n] = __builtin_amdgcn_mfma_f32_16x16x32_bf16(
                    a[m], b[n], acc[m][n], 0, 0, 0);

        if (pre) WRITE_B(cur ^ 1);       // convert + ds_write late
        __syncthreads();
    }

#pragma unroll
    for (int m = 0; m < 4; ++m) {
#pragma unroll
        for (int n = 0; n < 4; ++n) {
            int gr = bm0 + wr * 64 + m * 16 + rq;
            int gc = bn0 + wc * 64 + n * 16 + fr;
#pragma unroll
            for (int i = 0; i < 4; ++i)
                Cf[(size_t)(gr + i) * Vn + gc] = acc[m][n][i];
        }
    }
}

// ---------------------------------------------------------------------------
// PV kernel: C[Sn][Dn] = Pb @ Vt^T + R (per batch), K clamped at diagonal.
// 64x64 tile, 2x2 waves, BK=32, ring-3 LDS buffers, counted-vmcnt pipeline.
// ---------------------------------------------------------------------------
__global__ __launch_bounds__(256)
void k_pv(const u16* __restrict__ Pb, const u16* __restrict__ Vt,
          const float* __restrict__ R, float* __restrict__ Cf,
          u16* __restrict__ Cb) {
    int bm0 = blockIdx.y * 64;
    int bn0 = blockIdx.x * 64;
    int zb = blockIdx.z;
    const u16* A = Pb + (long long)zb * Sn * Sn;
    const u16* Bb = Vt + (long long)zb * (long long)Dn * Sn;
    const float* Rz = R + (long long)zb * Sn * Dn;
    float* Cfz = Cf + (long long)zb * Sn * Dn;
    u16* Cbz = Cb + (long long)zb * Sn * Dn;

    __shared__ alignas(16) u16 As[3][64 * 32];
    __shared__ alignas(16) u16 Bs[3][64 * 32];

    int tid = threadIdx.x;
    int lane = tid & 63, wave = tid >> 6;
    int wr = wave >> 1, wc = wave & 1;
    int fr = lane & 15, kq = lane >> 4, rq = kq * 4;

    int nt = (bm0 + 64) >> 5;  // 2..64 k-steps (causal clamp)

    auto RSTAGE = [&](int buf, int t) {
        int k0 = t << 5;
        int r = tid >> 2, co = (tid & 3) << 3;
        GLOAD16(&A[(size_t)(bm0 + r) * Sn + k0 + co], &As[buf][tid * 8]);
        GLOAD16(&Bb[(size_t)(bn0 + r) * Sn + k0 + co], &Bs[buf][tid * 8]);
    };

    f32x4 acc[2][2] = {};
    RSTAGE(0, 0);
    RSTAGE(1, 1);  // nt >= 2 always

    for (int t = 0; t < nt; ++t) {
        if (t + 1 < nt)
            asm volatile("s_waitcnt vmcnt(2)" ::: "memory");
        else
            asm volatile("s_waitcnt vmcnt(0)" ::: "memory");
        __builtin_amdgcn_s_barrier();
        __builtin_amdgcn_sched_barrier(0);
        if (t + 2 < nt) RSTAGE((t + 2) % 3, t + 2);

        int cur = t % 3;
        bf16x8 a[2], b[2];
#pragma unroll
        for (int m = 0; m < 2; ++m)
            a[m] = *(const bf16x8*)&As[cur]
                       [(wr * 32 + m * 16 + fr) * 32 + kq * 8];
#pragma unroll
        for (int n = 0; n < 2; ++n)
            b[n] = *(const bf16x8*)&Bs[cur]
                       [(wc * 32 + n * 16 + fr) * 32 + kq * 8];
#pragma unroll
        for (int m = 0; m < 2; ++m)
#pragma unroll
            for (int n = 0; n < 2; ++n)
                acc[m][n] = __builtin_amdgcn_mfma_f32_16x16x32_bf16(
                    a[m], b[n], acc[m][n], 0, 0, 0);
    }

#pragma unroll
    for (int m = 0; m < 2; ++m) {
#pragma unroll
        for (int n = 0; n < 2; ++n) {
            int gr = bm0 + wr * 32 + m * 16 + rq;
            int gc = bn0 + wc * 32 + n * 16 + fr;
#pragma unroll
            for (int i = 0; i < 4; ++i) {
                float v = acc[m][n][i];
                size_t idx = (size_t)(gr + i) * Dn + gc;
                v += Rz[idx];
                Cfz[idx] = v;
                Cbz[idx] = f2b(v);
            }
        }
    }
}

// ---------------------------------------------------------------------------
// Single-pass causal softmax: row (2048 f32) in 8 regs; writes bf16 probs in
// cols [0, ceil128(n)) (zeros beyond diagonal).
// ---------------------------------------------------------------------------
__global__ __launch_bounds__(256) void k_softmax(const float* __restrict__ Sc,
                                                 u16* __restrict__ Pb) {
    int bs = blockIdx.x;
    int b = bs >> 11, s = bs & 2047;
    const float* row = Sc + ((size_t)b << 22) + ((size_t)s << 11);
    u16* prow = Pb + ((size_t)b << 22) + ((size_t)s << 11);
    int tid = threadIdx.x;
    int n = s + 1;
    int nc = (n + 127) & ~127;

    float v[8];
#pragma unroll
    for (int j = 0; j < 8; ++j) {
        int t = tid + j * 256;
        v[j] = (t < n) ? row[t] : -INFINITY;
    }

    float m = v[0];
#pragma unroll
    for (int j = 1; j < 8; ++j) m = fmaxf(m, v[j]);
    m = wred_max(m);

    __shared__ float red[8];
    int lane = tid & 63, w = tid >> 6;
    if (lane == 0) red[w] = m;
    __syncthreads();
    m = fmaxf(fmaxf(red[0], red[1]), fmaxf(red[2], red[3]));

    float sum = 0.0f;
#pragma unroll
    for (int j = 0; j < 8; ++j) {
        v[j] = __expf(v[j] - m);
        sum += v[j];
    }
    sum = wred_sum(sum);
    if (lane == 0) red[4 + w] = sum;
    __syncthreads();
    float inv = 1.0f / (red[4] + red[5] + red[6] + red[7]);

#pragma unroll
    for (int j = 0; j < 8; ++j) {
        int t = tid + j * 256;
        if (t < nc) prow[t] = f2b(v[j] * inv);
    }
}

// ---------------------------------------------------------------------------
static void launch_layer(const float* XfIn, float* XfOut, u16* Xb,
                         const u16* Wqv, u16* Qb, u16* Vt, float* Sc, u16* Pb,
                         hipStream_t stream) {
    // QV = Xb @ Wqv^T ; bn0<256 -> Qb, bn0>=256 -> Vt (transposed); 256 blocks
    k_mfma<false, false, true, false, true, 64>
        <<<dim3(8, 32, 1), 256, 0, stream>>>(
            Xb, Wqv, nullptr, nullptr, Qb, Vt, BSn, 512, Dn, Dn, Dn, Dn, 1.0f,
            0, 0, 0, 0);
    // scores = 16 * Qb @ Xb^T (batched, causal blocks skipped)
    k_mfma<false, true, false, true, false, 128>
        <<<dim3(Sn / 128, Sn / 128, Bn), 256, 0, stream>>>(
            Qb, Xb, nullptr, Sc, nullptr, nullptr, Sn, Sn, Dn, Dn, Dn, Sn,
            16.0f, (long long)Sn * Dn, (long long)Sn * Dn, (long long)Sn * Sn,
            0);
    // softmax -> bf16 probs
    k_softmax<<<Bn * Sn, 256, 0, stream>>>(Sc, Pb);
    // Xout = Pb @ Vt^T + XfIn ; Xb = bf16(Xout); 64x64 ring-3, 256 blocks
    k_pv<<<dim3(Dn / 64, Sn / 64, Bn), 256, 0, stream>>>(Pb, Vt, XfIn, XfOut,
                                                         Xb);
}

extern "C" void kernel_launch(void* const* d_in, const int* in_sizes, int n_in,
                              void* d_out, int out_size, void* d_ws,
                              size_t ws_size, hipStream_t stream) {
    const int* inp = (const int*)d_in[0];
    // d_in[1] = mask — causal by construction, not read
    const float* E = (const float*)d_in[2];
    const float* P = (const float*)d_in[3];
    const float* WQK1 = (const float*)d_in[4];
    const float* WOV1 = (const float*)d_in[5];
    const float* WQK2 = (const float*)d_in[6];
    const float* WOV2 = (const float*)d_in[7];
    const float* WF = (const float*)d_in[8];
    const float* U = (const float*)d_in[9];
    float* out = (float*)d_out;

    char* p = (char*)d_ws;
    auto alloc = [&](size_t bytes) {
        void* r = (void*)p;
        p += (bytes + 255) & ~(size_t)255;
        return r;
    };

    float* XfA = (float*)alloc((size_t)BSn * Dn * 4);
    float* XfB = (float*)alloc((size_t)BSn * Dn * 4);
    float* Sc = (float*)alloc((size_t)Bn * Sn * Sn * 4);
    u16* Xb = (u16*)alloc((size_t)BSn * Dn * 2);
    u16* Qb = (u16*)alloc((size_t)BSn * Dn * 2);
    u16* Vt = (u16*)alloc((size_t)Bn * Dn * Sn * 2);
    u16* Fb = (u16*)alloc((size_t)BSn * Dn * 2);
    u16* Pb = (u16*)alloc((size_t)Bn * Sn * Sn * 2);
    u16* Wqv1 = (u16*)alloc((size_t)512 * Dn * 2);
    u16* Wqv2 = (u16*)alloc((size_t)512 * Dn * 2);
    u16* Wfb = (u16*)alloc((size_t)Dn * Dn * 2);

    // prep: weight converts + embed (no U convert)
    k_prep<<<4416, 256, 0, stream>>>(inp, E, P, WQK1, WOV1, WQK2, WOV2, WF,
                                     XfA, Xb, Wqv1, Wqv2, Wfb);

    // two attention blocks
    launch_layer(XfA, XfB, Xb, Wqv1, Qb, Vt, Sc, Pb, stream);
    launch_layer(XfB, XfA, Xb, Wqv2, Qb, Vt, Sc, Pb, stream);

    // FFN residual: Fb = bf16(XfA + Xb @ Wf^T); TN=64 -> 128 blocks
    k_mfma<true, false, true, false, false, 64>
        <<<dim3(4, 32, 1), 256, 0, stream>>>(
            Xb, Wfb, XfA, nullptr, Fb, nullptr, BSn, Dn, Dn, Dn, Dn, Dn, 1.0f,
            0, 0, 0, 0);

    // logits = Fb @ U^T -> d_out (f32); U converted in staging
    k_logits<25><<<dim3((Vn / 128) * (BSn / 128), 1, 1), 256, 0, stream>>>(
        Fb, U, out, BSn / 128);
}

// Round 10
// 262.156 us; speedup vs baseline: 1.0783x; 1.0783x over previous
//
#include <hip/hip_runtime.h>
#include <math.h>

#define Bn 2
#define Sn 2048
#define Vn 32000
#define Dn 256
#define BSn (Bn * Sn)

typedef unsigned short u16;
typedef __attribute__((ext_vector_type(8))) __bf16 bf16x8;
typedef __attribute__((ext_vector_type(4))) float f32x4;
typedef __attribute__((ext_vector_type(8))) unsigned short u16x8;
typedef __attribute__((ext_vector_type(4))) unsigned short u16x4;

__device__ __forceinline__ u16 f2b(float v) {
    union { __bf16 b; u16 u; } c;
    c.b = (__bf16)v;
    return c.u;
}

// async global->LDS, 16B per lane; LDS dest must be linear in lane order
#define GLOAD16(gp, lp)                                          \
    __builtin_amdgcn_global_load_lds(                            \
        (const __attribute__((address_space(1))) void*)(gp),     \
        (__attribute__((address_space(3))) void*)(lp), 16, 0, 0)

__device__ __forceinline__ float wred_max(float v) {
#pragma unroll
    for (int o = 32; o; o >>= 1) v = fmaxf(v, __shfl_xor(v, o, 64));
    return v;
}
__device__ __forceinline__ float wred_sum(float v) {
#pragma unroll
    for (int o = 32; o; o >>= 1) v += __shfl_xor(v, o, 64);
    return v;
}

// ---------------------------------------------------------------------------
// Prep: all weight converts + U convert + embed, one dispatch.
// ---------------------------------------------------------------------------
__global__ __launch_bounds__(256) void k_prep(
    const int* __restrict__ inp, const float* __restrict__ E,
    const float* __restrict__ P, const float* __restrict__ WQK1,
    const float* __restrict__ WOV1, const float* __restrict__ WQK2,
    const float* __restrict__ WOV2, const float* __restrict__ WF,
    const float* __restrict__ U, float* __restrict__ Xf, u16* __restrict__ Xb,
    u16* __restrict__ Wqv1, u16* __restrict__ Wqv2, u16* __restrict__ Wfb,
    u16* __restrict__ Ub) {
    int bid = blockIdx.x;
    if (bid < 320) {
        int w = bid >> 6, blk = bid & 63;
        const float* src;
        u16* dst;
        switch (w) {
            case 0: src = WQK1; dst = Wqv1; break;
            case 1: src = WOV1; dst = Wqv1 + Dn * Dn; break;
            case 2: src = WQK2; dst = Wqv2; break;
            case 3: src = WOV2; dst = Wqv2 + Dn * Dn; break;
            default: src = WF; dst = Wfb; break;
        }
        int i = (blk * 256 + threadIdx.x) * 4;
        float4 v = *(const float4*)&src[i];
        u16x4 o;
        o.x = f2b(v.x); o.y = f2b(v.y); o.z = f2b(v.z); o.w = f2b(v.w);
        *(u16x4*)&dst[i] = o;
    } else if (bid < 8320) {
        int i = ((bid - 320) * 256 + threadIdx.x) * 4;
        float4 v = *(const float4*)&U[i];
        u16x4 o;
        o.x = f2b(v.x); o.y = f2b(v.y); o.z = f2b(v.z); o.w = f2b(v.w);
        *(u16x4*)&Ub[i] = o;
    } else {
        int bs = bid - 8320;
        int d = threadIdx.x;
        int tok = inp[bs];
        int s = bs & (Sn - 1);
        float v = E[(size_t)tok * Dn + d] + P[(size_t)s * Dn + d];
        Xf[(size_t)bs * Dn + d] = v;
        Xb[(size_t)bs * Dn + d] = f2b(v);
    }
}

// ---------------------------------------------------------------------------
// MFMA GEMM: C[M,N] = alpha * A[M,K] @ B[N,K]^T (+R). bf16 in, f32 acc.
// 128xTN tile (TN=128 or 64), BK=32, 256 thr, dual-buffer LDS, 2-phase
// pipeline. QV_SPLIT: x-tiles bn0>=256 scatter-write transposed V.
// CHUNK>0: 1-D launch; bijective XCD swizzle + chunked x-remap (L2 locality).
// ---------------------------------------------------------------------------
template <bool HAS_RES, bool OUT_F32, bool OUT_BF16, bool CAUSAL_SKIP,
          bool QV_SPLIT, int CHUNK, int TN>
__global__ __launch_bounds__(256)
void k_mfma(const u16* __restrict__ A, const u16* __restrict__ Bb,
            const float* __restrict__ R, float* __restrict__ Cf,
            u16* __restrict__ Cb, u16* __restrict__ Ct, int M, int N, int K,
            int lda, int ldb, int ldc, float alpha, long long sA, long long sB,
            long long sC, long long sR, int ytiles) {
    int bx, by;
    if (CHUNK > 0) {
        int nwg = gridDim.x;
        int q = nwg >> 3;
        int bid = blockIdx.x;
        int wg = (bid & 7) * q + (bid >> 3);  // bijective (nwg % 8 == 0)
        int per = CHUNK * ytiles;
        int ch = wg / per, rr = wg % per;
        bx = ch * CHUNK + rr % CHUNK;
        by = rr / CHUNK;
    } else {
        bx = blockIdx.x;
        by = blockIdx.y;
    }
    int bm0 = by * 128;
    int bn0 = bx * TN;
    if (CAUSAL_SKIP && bn0 > bm0 + 127) return;

    int zb = blockIdx.z;
    A += (long long)zb * sA;
    Bb += (long long)zb * sB;
    if (HAS_RES) R += (long long)zb * sR;
    if (OUT_F32) Cf += (long long)zb * sC;
    if (OUT_BF16) Cb += (long long)zb * sC;

    __shared__ alignas(16) u16 As[2][128 * 32];
    __shared__ alignas(16) u16 Bs[2][TN * 32];

    int tid = threadIdx.x;
    int lane = tid & 63;
    int wave = tid >> 6;

    constexpr int MF = (TN == 128) ? 4 : 2;
    int wr, wc;
    if (TN == 128) {
        wr = wave >> 1;
        wc = wave & 1;
    } else {
        wr = wave;
        wc = 0;
    }

    int fr = lane & 15;
    int kq = lane >> 4;
    int rq = kq * 4;

    f32x4 acc[MF][4] = {};

    int nt = K >> 5;

    auto STAGE = [&](int buf, int k0) {
#pragma unroll
        for (int c = 0; c < 2; ++c) {
            int idx = tid + c * 256;
            int r = idx >> 2, co = (idx & 3) << 3;
            GLOAD16(&A[(size_t)(bm0 + r) * lda + k0 + co], &As[buf][idx * 8]);
        }
#pragma unroll
        for (int c = 0; c < TN / 64; ++c) {
            int idx = tid + c * 256;
            int r = idx >> 2, co = (idx & 3) << 3;
            GLOAD16(&Bb[(size_t)(bn0 + r) * ldb + k0 + co], &Bs[buf][idx * 8]);
        }
    };

    STAGE(0, 0);
    __syncthreads();

    for (int t = 0; t < nt; ++t) {
        int cur = t & 1;
        if (t + 1 < nt) STAGE(cur ^ 1, (t + 1) << 5);

        bf16x8 a[MF], b[4];
#pragma unroll
        for (int m = 0; m < MF; ++m)
            a[m] = *(const bf16x8*)&As[cur]
                       [(wr * (MF * 16) + m * 16 + fr) * 32 + kq * 8];
#pragma unroll
        for (int n = 0; n < 4; ++n)
            b[n] = *(const bf16x8*)&Bs[cur]
                       [(wc * 64 + n * 16 + fr) * 32 + kq * 8];
#pragma unroll
        for (int m = 0; m < MF; ++m)
#pragma unroll
            for (int n = 0; n < 4; ++n)
                acc[m][n] = __builtin_amdgcn_mfma_f32_16x16x32_bf16(
                    a[m], b[n], acc[m][n], 0, 0, 0);
        __syncthreads();
    }

    // ---- epilogue; C/D layout: col = lane&15, row = (lane>>4)*4 + i ----
    if (QV_SPLIT && bn0 >= 256) {
#pragma unroll
        for (int m = 0; m < MF; ++m) {
#pragma unroll
            for (int n = 0; n < 4; ++n) {
                int gr = bm0 + wr * (MF * 16) + m * 16 + rq;  // s-global
                int gc = bn0 + wc * 64 + n * 16 + fr - 256;   // d
                int bb = gr / Sn;
                int ss = gr % Sn;
                u16x4 o;
#pragma unroll
                for (int i = 0; i < 4; ++i) o[i] = f2b(acc[m][n][i]);
                *(u16x4*)&Ct[((size_t)bb * Dn + gc) * Sn + ss] = o;
            }
        }
        return;
    }

#pragma unroll
    for (int m = 0; m < MF; ++m) {
#pragma unroll
        for (int n = 0; n < 4; ++n) {
            int gr = bm0 + wr * (MF * 16) + m * 16 + rq;
            int gc = bn0 + wc * 64 + n * 16 + fr;
#pragma unroll
            for (int i = 0; i < 4; ++i) {
                float v = acc[m][n][i] * alpha;
                size_t idx = (size_t)(gr + i) * ldc + gc;
                if (HAS_RES) v += R[idx];
                if (OUT_F32) Cf[idx] = v;
                if (OUT_BF16) Cb[idx] = f2b(v);
            }
        }
    }
}

// ---------------------------------------------------------------------------
// PV kernel: C[Sn][Dn] = Pb @ Vt^T + R (per batch), K clamped at diagonal.
// 64x64 tile, 2x2 waves, BK=32, ring-6 LDS buffers, counted-vmcnt pipeline
// keeping up to 4 future stages (8 loads) in flight across the raw barrier.
// Grid (Dn/64, Sn/64, Bn) = 256 blocks = 1/CU; 48 KB LDS.
// ---------------------------------------------------------------------------
__global__ __launch_bounds__(256)
void k_pv(const u16* __restrict__ Pb, const u16* __restrict__ Vt,
          const float* __restrict__ R, float* __restrict__ Cf,
          u16* __restrict__ Cb) {
    int bm0 = blockIdx.y * 64;
    int bn0 = blockIdx.x * 64;
    int zb = blockIdx.z;
    const u16* A = Pb + (long long)zb * Sn * Sn;
    const u16* Bb = Vt + (long long)zb * (long long)Dn * Sn;
    const float* Rz = R + (long long)zb * Sn * Dn;
    float* Cfz = Cf + (long long)zb * Sn * Dn;
    u16* Cbz = Cb + (long long)zb * Sn * Dn;

    __shared__ alignas(16) u16 As[6][64 * 32];
    __shared__ alignas(16) u16 Bs[6][64 * 32];

    int tid = threadIdx.x;
    int lane = tid & 63, wave = tid >> 6;
    int wr = wave >> 1, wc = wave & 1;
    int fr = lane & 15, kq = lane >> 4, rq = kq * 4;

    int nt = (bm0 + 64) >> 5;  // 2..64 k-steps (causal clamp)

    auto RSTAGE = [&](int buf, int t) {
        int k0 = t << 5;
        int r = tid >> 2, co = (tid & 3) << 3;
        GLOAD16(&A[(size_t)(bm0 + r) * Sn + k0 + co], &As[buf][tid * 8]);
        GLOAD16(&Bb[(size_t)(bn0 + r) * Sn + k0 + co], &Bs[buf][tid * 8]);
    };

    f32x4 acc[2][2] = {};
    // prologue: stage up to 5 tiles ahead (stages 0..4)
#pragma unroll
    for (int s = 0; s < 5; ++s)
        if (s < nt) RSTAGE(s, s);

    for (int t = 0; t < nt; ++t) {
        // retire own stage(t) loads; up to 4 future stages (8 loads) stay
        // in flight. Barrier after wait -> all waves have stage(t) resident.
        int rem = nt - 1 - t;
        if (rem >= 4)
            asm volatile("s_waitcnt vmcnt(8)" ::: "memory");
        else if (rem == 3)
            asm volatile("s_waitcnt vmcnt(6)" ::: "memory");
        else if (rem == 2)
            asm volatile("s_waitcnt vmcnt(4)" ::: "memory");
        else if (rem == 1)
            asm volatile("s_waitcnt vmcnt(2)" ::: "memory");
        else
            asm volatile("s_waitcnt vmcnt(0)" ::: "memory");
        __builtin_amdgcn_s_barrier();
        __builtin_amdgcn_sched_barrier(0);
        if (t + 5 < nt) RSTAGE((t + 5) % 6, t + 5);

        int cur = t % 6;
        bf16x8 a[2], b[2];
#pragma unroll
        for (int m = 0; m < 2; ++m)
            a[m] = *(const bf16x8*)&As[cur]
                       [(wr * 32 + m * 16 + fr) * 32 + kq * 8];
#pragma unroll
        for (int n = 0; n < 2; ++n)
            b[n] = *(const bf16x8*)&Bs[cur]
                       [(wc * 32 + n * 16 + fr) * 32 + kq * 8];
#pragma unroll
        for (int m = 0; m < 2; ++m)
#pragma unroll
            for (int n = 0; n < 2; ++n)
                acc[m][n] = __builtin_amdgcn_mfma_f32_16x16x32_bf16(
                    a[m], b[n], acc[m][n], 0, 0, 0);
    }

#pragma unroll
    for (int m = 0; m < 2; ++m) {
#pragma unroll
        for (int n = 0; n < 2; ++n) {
            int gr = bm0 + wr * 32 + m * 16 + rq;
            int gc = bn0 + wc * 32 + n * 16 + fr;
#pragma unroll
            for (int i = 0; i < 4; ++i) {
                float v = acc[m][n][i];
                size_t idx = (size_t)(gr + i) * Dn + gc;
                v += Rz[idx];
                Cfz[idx] = v;
                Cbz[idx] = f2b(v);
            }
        }
    }
}

// ---------------------------------------------------------------------------
// Single-pass causal softmax: row (2048 f32) loaded as float4 (8/thread);
// writes bf16 probs in cols [0, ceil128(n)) (zeros beyond diagonal).
// ---------------------------------------------------------------------------
__global__ __launch_bounds__(256) void k_softmax(const float* __restrict__ Sc,
                                                 u16* __restrict__ Pb) {
    int bs = blockIdx.x;
    int b = bs >> 11, s = bs & 2047;
    const float* row = Sc + ((size_t)b << 22) + ((size_t)s << 11);
    const float4* row4 = (const float4*)row;
    u16* prow = Pb + ((size_t)b << 22) + ((size_t)s << 11);
    int tid = threadIdx.x;
    int n = s + 1;
    int nc = (n + 127) & ~127;

    float v[8];
#pragma unroll
    for (int j = 0; j < 2; ++j) {
        float4 q = row4[tid + j * 256];
        int e0 = (tid + j * 256) * 4;
        v[j * 4 + 0] = (e0 + 0 < n) ? q.x : -INFINITY;
        v[j * 4 + 1] = (e0 + 1 < n) ? q.y : -INFINITY;
        v[j * 4 + 2] = (e0 + 2 < n) ? q.z : -INFINITY;
        v[j * 4 + 3] = (e0 + 3 < n) ? q.w : -INFINITY;
    }

    float m = v[0];
#pragma unroll
    for (int j = 1; j < 8; ++j) m = fmaxf(m, v[j]);
    m = wred_max(m);

    __shared__ float red[8];
    int lane = tid & 63, w = tid >> 6;
    if (lane == 0) red[w] = m;
    __syncthreads();
    m = fmaxf(fmaxf(red[0], red[1]), fmaxf(red[2], red[3]));

    float sum = 0.0f;
#pragma unroll
    for (int j = 0; j < 8; ++j) {
        v[j] = __expf(v[j] - m);  // exp(-inf)=0 handles the mask
        sum += v[j];
    }
    sum = wred_sum(sum);
    if (lane == 0) red[4 + w] = sum;
    __syncthreads();
    float inv = 1.0f / (red[4] + red[5] + red[6] + red[7]);

#pragma unroll
    for (int j = 0; j < 2; ++j) {
        int e0 = (tid + j * 256) * 4;
        if (e0 < nc) {
            u16x4 o;
            o[0] = f2b(v[j * 4 + 0] * inv);
            o[1] = f2b(v[j * 4 + 1] * inv);
            o[2] = f2b(v[j * 4 + 2] * inv);
            o[3] = f2b(v[j * 4 + 3] * inv);
            *(u16x4*)&prow[e0] = o;
        }
    }
}

// ---------------------------------------------------------------------------
static void launch_layer(const float* XfIn, float* XfOut, u16* Xb,
                         const u16* Wqv, u16* Qb, u16* Vt, float* Sc, u16* Pb,
                         hipStream_t stream) {
    // QV = Xb @ Wqv^T ; bn0<256 -> Qb, bn0>=256 -> Vt (transposed); 256 blocks
    k_mfma<false, false, true, false, true, 0, 64>
        <<<dim3(8, 32, 1), 256, 0, stream>>>(
            Xb, Wqv, nullptr, nullptr, Qb, Vt, BSn, 512, Dn, Dn, Dn, Dn, 1.0f,
            0, 0, 0, 0, 0);
    // scores = 16 * Qb @ Xb^T ; TN=64 -> 544 active blocks (2.1/CU)
    k_mfma<false, true, false, true, false, 0, 64>
        <<<dim3(Sn / 64, Sn / 128, Bn), 256, 0, stream>>>(
            Qb, Xb, nullptr, Sc, nullptr, nullptr, Sn, Sn, Dn, Dn, Dn, Sn,
            16.0f, (long long)Sn * Dn, (long long)Sn * Dn, (long long)Sn * Sn,
            0, 0);
    // softmax -> bf16 probs
    k_softmax<<<Bn * Sn, 256, 0, stream>>>(Sc, Pb);
    // Xout = Pb @ Vt^T + XfIn ; Xb = bf16(Xout); 64x64 ring-6, 256 blocks
    k_pv<<<dim3(Dn / 64, Sn / 64, Bn), 256, 0, stream>>>(Pb, Vt, XfIn, XfOut,
                                                         Xb);
}

extern "C" void kernel_launch(void* const* d_in, const int* in_sizes, int n_in,
                              void* d_out, int out_size, void* d_ws,
                              size_t ws_size, hipStream_t stream) {
    const int* inp = (const int*)d_in[0];
    // d_in[1] = mask — causal by construction, not read
    const float* E = (const float*)d_in[2];
    const float* P = (const float*)d_in[3];
    const float* WQK1 = (const float*)d_in[4];
    const float* WOV1 = (const float*)d_in[5];
    const float* WQK2 = (const float*)d_in[6];
    const float* WOV2 = (const float*)d_in[7];
    const float* WF = (const float*)d_in[8];
    const float* U = (const float*)d_in[9];
    float* out = (float*)d_out;

    char* p = (char*)d_ws;
    auto alloc = [&](size_t bytes) {
        void* r = (void*)p;
        p += (bytes + 255) & ~(size_t)255;
        return r;
    };

    float* XfA = (float*)alloc((size_t)BSn * Dn * 4);
    float* XfB = (float*)alloc((size_t)BSn * Dn * 4);
    float* Sc = (float*)alloc((size_t)Bn * Sn * Sn * 4);
    u16* Xb = (u16*)alloc((size_t)BSn * Dn * 2);
    u16* Qb = (u16*)alloc((size_t)BSn * Dn * 2);
    u16* Vt = (u16*)alloc((size_t)Bn * Dn * Sn * 2);
    u16* Fb = (u16*)alloc((size_t)BSn * Dn * 2);
    u16* Pb = (u16*)alloc((size_t)Bn * Sn * Sn * 2);
    u16* Wqv1 = (u16*)alloc((size_t)512 * Dn * 2);
    u16* Wqv2 = (u16*)alloc((size_t)512 * Dn * 2);
    u16* Wfb = (u16*)alloc((size_t)Dn * Dn * 2);
    u16* Ub = (u16*)alloc((size_t)Vn * Dn * 2);

    // prep: all converts + embed, one dispatch
    k_prep<<<12416, 256, 0, stream>>>(inp, E, P, WQK1, WOV1, WQK2, WOV2, WF, U,
                                      XfA, Xb, Wqv1, Wqv2, Wfb, Ub);

    // two attention blocks
    launch_layer(XfA, XfB, Xb, Wqv1, Qb, Vt, Sc, Pb, stream);
    launch_layer(XfB, XfA, Xb, Wqv2, Qb, Vt, Sc, Pb, stream);

    // FFN residual: Fb = bf16(XfA + Xb @ Wf^T); TN=64 -> 128 blocks
    k_mfma<true, false, true, false, false, 0, 64>
        <<<dim3(4, 32, 1), 256, 0, stream>>>(
            Xb, Wfb, XfA, nullptr, Fb, nullptr, BSn, Dn, Dn, Dn, Dn, Dn, 1.0f,
            0, 0, 0, 0, 0);

    // logits = Fb @ Ub^T -> d_out (f32); XCD-bijective + chunked x-remap
    k_mfma<false, true, false, false, false, 25, 128>
        <<<dim3((Vn / 128) * (BSn / 128), 1, 1), 256, 0, stream>>>(
            Fb, Ub, nullptr, out, nullptr, nullptr, BSn, Vn, Dn, Dn, Dn, Vn,
            1.0f, 0, 0, 0, 0, BSn / 128);
}